// Round 4
// baseline (352.256 us; speedup 1.0000x reference)
//
#include <hip/hip_runtime.h>

#define N_NODES 25600
#define N_EDGES 204800
#define EE (N_EDGES + N_NODES)   // 230400 edges incl. self loops
#define IN_CH 6
#define HID 64
#define HEADS 4
#define G_GRAPHS 512
#define T_STEPS 50
#define OUT_DIM 30
#define NEG_SLOPE 0.2f
#define BN_INV 0.9999950000374997f   // 1/sqrt(1+1e-5)

__device__ __forceinline__ float lrelu_(float x){ return x > 0.f ? x : NEG_SLOPE * x; }
__device__ __forceinline__ float elu_(float x){ return x > 0.f ? x : __expf(x) - 1.f; }
__device__ __forceinline__ float sigmoid_(float x){
    return __builtin_amdgcn_rcpf(1.f + __expf(-x));
}
// stable fast tanh: 1 - 2/(1+e^{2x})
__device__ __forceinline__ float tanh_(float x){
    return 1.f - 2.f * __builtin_amdgcn_rcpf(1.f + __expf(2.f * x));
}
__device__ __forceinline__ float bcast_(float v, int l){
    return __int_as_float(__builtin_amdgcn_readlane(__float_as_int(v), l));
}

// ---------------- CSR build (sort edges by dst) ----------------
__global__ void count_k(const int* __restrict__ ei, int* __restrict__ counts){
    int e = blockIdx.x * 256 + threadIdx.x;
    if (e >= EE) return;
    int dst = (e < N_EDGES) ? ei[N_EDGES + e] : (e - N_EDGES);
    atomicAdd(&counts[dst], 1);
}

__global__ void scan_k(const int* __restrict__ counts, int* __restrict__ row_ptr,
                       int* __restrict__ cursor){
    __shared__ int part[1024];
    int t = threadIdx.x;
    const int CH = N_NODES / 1024;           // 25
    int base = t * CH;
    int s = 0;
    for (int i = 0; i < CH; i++) s += counts[base + i];
    part[t] = s;
    __syncthreads();
    for (int off = 1; off < 1024; off <<= 1){
        int v = (t >= off) ? part[t - off] : 0;
        __syncthreads();
        part[t] += v;
        __syncthreads();
    }
    int run = (t > 0) ? part[t - 1] : 0;
    for (int i = 0; i < CH; i++){
        int cv = counts[base + i];
        row_ptr[base + i] = run;
        cursor[base + i]  = run;
        run += cv;
    }
    if (t == 1023) row_ptr[N_NODES] = run;
}

__global__ void scatter_k(const int* __restrict__ ei, int* __restrict__ cursor,
                          int* __restrict__ ssrc){
    int e = blockIdx.x * 256 + threadIdx.x;
    if (e >= EE) return;
    int src, dst;
    if (e < N_EDGES){ src = ei[e]; dst = ei[N_EDGES + e]; }
    else            { src = dst = e - N_EDGES; }
    int pos = atomicAdd(&cursor[dst], 1);
    ssrc[pos] = src;
}

// ---------------- layer-1 score prep ----------------
// Wa_src[k][h] = sum_c W1[k][h*64+c] * a_src[h][c]  (6x4), same for dst.
__global__ void wa_k(const float* __restrict__ W1, const float* __restrict__ asw,
                     const float* __restrict__ adw, float* __restrict__ waS,
                     float* __restrict__ waD){
    int t = threadIdx.x;              // 48 useful threads
    if (t >= 48) return;
    int k = t >> 3, h = (t >> 1) & 3, which = t & 1;
    const float* a = which ? adw : asw;
    float s = 0.f;
    #pragma unroll
    for (int c = 0; c < 64; c++) s += W1[k * 256 + h * 64 + c] * a[h * 64 + c];
    (which ? waD : waS)[k * 4 + h] = s;
}

// per-node scores: as1[n][h] = x[n] . waS[:,h], ad1 likewise
__global__ void ns_k(const float* __restrict__ x, const float* __restrict__ waS,
                     const float* __restrict__ waD, float* __restrict__ as1,
                     float* __restrict__ ad1){
    int n = blockIdx.x * 256 + threadIdx.x;
    float xv[IN_CH];
    #pragma unroll
    for (int k = 0; k < IN_CH; k++) xv[k] = x[n * IN_CH + k];
    float sv[4] = {0.f, 0.f, 0.f, 0.f}, dv[4] = {0.f, 0.f, 0.f, 0.f};
    #pragma unroll
    for (int k = 0; k < IN_CH; k++){
        #pragma unroll
        for (int h = 0; h < 4; h++){
            sv[h] += xv[k] * waS[k * 4 + h];
            dv[h] += xv[k] * waD[k * 4 + h];
        }
    }
    *(float4*)&as1[n * 4] = make_float4(sv[0], sv[1], sv[2], sv[3]);
    *(float4*)&ad1[n * 4] = make_float4(dv[0], dv[1], dv[2], dv[3]);
}

// ---------------- GAT layer 1: aggregate in x-space, then transform (linearity) ----------
// out[n] = (sum_j alpha_j x_j) @ W1 ; gathers 24B of x per edge instead of 1KB of h1_pre.
__global__ void gat1_aggx(const float* __restrict__ x, const float* __restrict__ as1,
                          const float* __restrict__ ad1, const int* __restrict__ row_ptr,
                          const int* __restrict__ ssrc, const float* __restrict__ W1,
                          const float* __restrict__ b1, const float* __restrict__ g1,
                          const float* __restrict__ be1, float* __restrict__ h1_act){
    __shared__ float w1s[IN_CH * 256];   // 6 KB
    int tid = threadIdx.x;
    for (int i = tid; i < IN_CH * 256; i += 256) w1s[i] = W1[i];
    __syncthreads();
    int wv = tid >> 6, lane = tid & 63;
    int n = blockIdx.x * 4 + wv;
    int s0 = row_ptr[n], s1 = row_ptr[n + 1];
    float4 adn = *(const float4*)&ad1[n * 4];
    float xs0[IN_CH] = {}, xs1[IN_CH] = {}, xs2[IN_CH] = {}, xs3[IN_CH] = {};
    float d0 = 0.f, d1 = 0.f, d2 = 0.f, d3 = 0.f;
    for (int j = s0; j < s1; j++){
        int s = ssrc[j];
        float4 as = *(const float4*)&as1[s * 4];
        float e0 = __expf(lrelu_(as.x + adn.x));
        float e1 = __expf(lrelu_(as.y + adn.y));
        float e2 = __expf(lrelu_(as.z + adn.z));
        float e3 = __expf(lrelu_(as.w + adn.w));
        d0 += e0; d1 += e1; d2 += e2; d3 += e3;
        const float2* xp = (const float2*)(x + (size_t)s * IN_CH);  // s*6 even -> 8B aligned
        float2 xa = xp[0], xb = xp[1], xc = xp[2];
        float xv[IN_CH] = {xa.x, xa.y, xb.x, xb.y, xc.x, xc.y};
        #pragma unroll
        for (int k = 0; k < IN_CH; k++){
            xs0[k] += e0 * xv[k];
            xs1[k] += e1 * xv[k];
            xs2[k] += e2 * xv[k];
            xs3[k] += e3 * xv[k];
        }
    }
    float r0 = 1.f / d0, r1 = 1.f / d1, r2 = 1.f / d2, r3 = 1.f / d3;
    // transform: out[h*64+lane] = (xs_h/d_h) . W1[:, h*64+lane]
    #pragma unroll
    for (int h = 0; h < 4; h++){
        const float* xsh = (h == 0) ? xs0 : (h == 1) ? xs1 : (h == 2) ? xs2 : xs3;
        float rh = (h == 0) ? r0 : (h == 1) ? r1 : (h == 2) ? r2 : r3;
        int col = h * 64 + lane;
        float acc = 0.f;
        #pragma unroll
        for (int k = 0; k < IN_CH; k++) acc += xsh[k] * w1s[k * 256 + col];
        float v = acc * rh + b1[col];
        v = g1[col] * (v * BN_INV) + be1[col];
        h1_act[(size_t)n * 256 + col] = elu_(v);
    }
}

// ---------------- GAT layer 2 transform: tiled SGEMM h2_pre = h1_act @ W2 + fused scores ----
#define TM 64
#define KT 32
#define APAD 4
__global__ __launch_bounds__(256) void gat2_tr(const float* __restrict__ h1_act,
                        const float* __restrict__ W2,
                        const float* __restrict__ asw, const float* __restrict__ adw,
                        float* __restrict__ h2_pre, float* __restrict__ as2,
                        float* __restrict__ ad2){
    __shared__ float As[TM][KT + APAD];
    __shared__ float Bs[KT][64];
    int tx = threadIdx.x;
    int rg = tx >> 4;
    int cg = tx & 15;
    int r0 = rg * 4, c0 = cg * 4;
    int rowBase = blockIdx.x * TM;
    float acc[4][4] = {};
    for (int k0 = 0; k0 < 256; k0 += KT){
        #pragma unroll
        for (int it = 0; it < 2; it++){
            int i = tx + it * 256;
            int row = i >> 3;
            int c4  = (i & 7) * 4;
            *(float4*)&As[row][c4] =
                *(const float4*)(h1_act + (size_t)(rowBase + row) * 256 + k0 + c4);
        }
        #pragma unroll
        for (int it = 0; it < 2; it++){
            int i = tx + it * 256;
            int row = i >> 4;
            int c4  = (i & 15) * 4;
            *(float4*)&Bs[row][c4] = *(const float4*)(W2 + (size_t)(k0 + row) * 64 + c4);
        }
        __syncthreads();
        #pragma unroll
        for (int kq = 0; kq < KT; kq += 4){
            float4 b0 = *(float4*)&Bs[kq + 0][c0];
            float4 b1v = *(float4*)&Bs[kq + 1][c0];
            float4 b2v = *(float4*)&Bs[kq + 2][c0];
            float4 b3 = *(float4*)&Bs[kq + 3][c0];
            #pragma unroll
            for (int i = 0; i < 4; i++){
                float4 a = *(float4*)&As[r0 + i][kq];
                acc[i][0] += a.x * b0.x + a.y * b1v.x + a.z * b2v.x + a.w * b3.x;
                acc[i][1] += a.x * b0.y + a.y * b1v.y + a.z * b2v.y + a.w * b3.y;
                acc[i][2] += a.x * b0.z + a.y * b1v.z + a.z * b2v.z + a.w * b3.z;
                acc[i][3] += a.x * b0.w + a.y * b1v.w + a.z * b2v.w + a.w * b3.w;
            }
        }
        __syncthreads();
    }
    float aw0 = asw[c0], aw1 = asw[c0+1], aw2 = asw[c0+2], aw3 = asw[c0+3];
    float dw0 = adw[c0], dw1 = adw[c0+1], dw2 = adw[c0+2], dw3 = adw[c0+3];
    #pragma unroll
    for (int i = 0; i < 4; i++){
        int row = rowBase + r0 + i;
        *(float4*)(h2_pre + (size_t)row * 64 + c0) =
            make_float4(acc[i][0], acc[i][1], acc[i][2], acc[i][3]);
        float sA = acc[i][0]*aw0 + acc[i][1]*aw1 + acc[i][2]*aw2 + acc[i][3]*aw3;
        float sD = acc[i][0]*dw0 + acc[i][1]*dw1 + acc[i][2]*dw2 + acc[i][3]*dw3;
        #pragma unroll
        for (int off = 8; off; off >>= 1){
            sA += __shfl_xor(sA, off);
            sD += __shfl_xor(sD, off);
        }
        if (cg == 0){ as2[row] = sA; ad2[row] = sD; }
    }
}

// ---------------- GAT layer 2 aggregate (single-pass) + bias + BN + ELU + scatter ----------------
__global__ void gat2_agg(const float* __restrict__ h2_pre, const float* __restrict__ as2,
                         const float* __restrict__ ad2, const int* __restrict__ row_ptr,
                         const int* __restrict__ ssrc,
                         const float* __restrict__ b2, const float* __restrict__ g2,
                         const float* __restrict__ be2,
                         const int* __restrict__ batch, const int* __restrict__ ntime,
                         float* __restrict__ xseq){
    int wv = threadIdx.x >> 6, lane = threadIdx.x & 63;
    int n = blockIdx.x * 4 + wv;
    int s0 = row_ptr[n], s1 = row_ptr[n + 1];
    float adn = ad2[n];
    float denom = 0.f, acc = 0.f;
    for (int j = s0; j < s1; j++){
        int s = ssrc[j];
        float e = __expf(lrelu_(as2[s] + adn));
        denom += e;
        acc += e * h2_pre[(size_t)s * 64 + lane];
    }
    float v = acc / denom + b2[lane];
    v = g2[lane] * (v * BN_INV) + be2[lane];
    v = elu_(v);
    int pos = batch[n] * T_STEPS + ntime[n];
    xseq[(size_t)pos * 64 + lane] = v;
}

// ---------------- gx = xseq @ Wih^T + (bih + bhh) ----------------
__global__ __launch_bounds__(256) void gx_k(const float* __restrict__ xseq,
        const float* __restrict__ Wih, const float* __restrict__ bih,
        const float* __restrict__ bhh, float* __restrict__ gx){
    __shared__ float As[64][68];
    __shared__ float Bs[64][128];
    int tx = threadIdx.x;
    int rowBase = blockIdx.x * 64;
    int colBase = blockIdx.y * 128;
    #pragma unroll
    for (int it = 0; it < 4; it++){
        int i = tx + it * 256;
        int r = i >> 4;
        int c4 = (i & 15) * 4;
        *(float4*)&As[r][c4] = *(const float4*)(xseq + (size_t)(rowBase + r) * 64 + c4);
    }
    #pragma unroll
    for (int it = 0; it < 8; it++){
        int i = tx + it * 256;
        int jj = i & 127;
        int k4 = (i >> 7) * 4;
        float4 wv = *(const float4*)(Wih + (size_t)(colBase + jj) * 64 + k4);
        Bs[k4 + 0][jj] = wv.x;
        Bs[k4 + 1][jj] = wv.y;
        Bs[k4 + 2][jj] = wv.z;
        Bs[k4 + 3][jj] = wv.w;
    }
    __syncthreads();
    int rg = tx >> 5;
    int cg = tx & 31;
    int r0 = rg * 8, c0 = cg * 4;
    float acc[8][4] = {};
    #pragma unroll
    for (int kq = 0; kq < 64; kq += 4){
        float4 b0 = *(float4*)&Bs[kq + 0][c0];
        float4 b1 = *(float4*)&Bs[kq + 1][c0];
        float4 b2 = *(float4*)&Bs[kq + 2][c0];
        float4 b3 = *(float4*)&Bs[kq + 3][c0];
        #pragma unroll
        for (int i = 0; i < 8; i++){
            float4 a = *(float4*)&As[r0 + i][kq];
            acc[i][0] += a.x * b0.x + a.y * b1.x + a.z * b2.x + a.w * b3.x;
            acc[i][1] += a.x * b0.y + a.y * b1.y + a.z * b2.y + a.w * b3.y;
            acc[i][2] += a.x * b0.z + a.y * b1.z + a.z * b2.z + a.w * b3.z;
            acc[i][3] += a.x * b0.w + a.y * b1.w + a.z * b2.w + a.w * b3.w;
        }
    }
    int col = colBase + c0;
    float4 bb = make_float4(bih[col] + bhh[col], bih[col+1] + bhh[col+1],
                            bih[col+2] + bhh[col+2], bih[col+3] + bhh[col+3]);
    #pragma unroll
    for (int i = 0; i < 8; i++){
        int row = rowBase + r0 + i;
        *(float4*)(gx + (size_t)row * 256 + col) =
            make_float4(acc[i][0] + bb.x, acc[i][1] + bb.y,
                        acc[i][2] + bb.z, acc[i][3] + bb.w);
    }
}

// ---------------- LSTM over T=50 steps + final FC, one block per graph ----------------
// h broadcast via v_readlane from each wave's own registers (VALU pipe) -- the per-step
// epilogue is computed redundantly by all 4 waves, so every wave's lane l holds h[l].
// LDS carries ONLY the 256-float gates exchange (1 write + 4 stride-64 reads + 1 barrier
// per step; lanes hit 32 banks 2-way = free). gx preloaded into 50 VGPRs (fully
// unrolled, statically indexed) -> zero global memory in the recurrence -> the
// barrier's vmcnt(0) drain has nothing to wait on.
__global__ __launch_bounds__(256, 2) void lstm_k(const float* __restrict__ gx,
        const float* __restrict__ Whh,
        const float* __restrict__ Wfc, const float* __restrict__ bfc,
        float* __restrict__ out){
    int g = blockIdx.x;
    int j = threadIdx.x;
    int lane = j & 63;
    __shared__ float gates[2][256];
    float4 whh[16];
    const float4* Hr = (const float4*)(Whh + j * 64);
    #pragma unroll
    for (int k = 0; k < 16; k++) whh[k] = Hr[k];
    // preload the full gx sequence for this thread: gxr[t] = gx[g][t][j]
    float gxr[T_STEPS];
    const float* gxg = gx + (size_t)g * T_STEPS * 256 + j;
    #pragma unroll
    for (int t = 0; t < T_STEPS; t++) gxr[t] = gxg[t * 256];
    float c = 0.f, hn = 0.f;   // hn: this lane's h[lane], identical across waves
    #pragma unroll
    for (int t = 0; t < T_STEPS; t++){
        int buf = t & 1;
        float a0 = gxr[t], a1 = 0.f, a2 = 0.f, a3 = 0.f;
        #pragma unroll
        for (int k = 0; k < 16; k++){
            float4 wv = whh[k];
            a0 += wv.x * bcast_(hn, 4 * k + 0);
            a1 += wv.y * bcast_(hn, 4 * k + 1);
            a2 += wv.z * bcast_(hn, 4 * k + 2);
            a3 += wv.w * bcast_(hn, 4 * k + 3);
        }
        gates[buf][j] = (a0 + a1) + (a2 + a3);
        __syncthreads();
        // redundant epilogue on all 256 threads -> every wave holds full h in registers
        float iv = gates[buf][lane];
        float fv = gates[buf][64 + lane];
        float gv = gates[buf][128 + lane];
        float ov = gates[buf][192 + lane];
        c = sigmoid_(fv) * c + sigmoid_(iv) * tanh_(gv);
        hn = sigmoid_(ov) * tanh_(c);
        // double-buffered gates: next step writes buf^1, safe without a 2nd barrier
    }
    // final FC
    if (j < 64) gates[0][j] = hn;
    __syncthreads();
    if (j < OUT_DIM){
        float acc = bfc[j];
        #pragma unroll
        for (int k = 0; k < 64; k++) acc += gates[0][k] * Wfc[k * OUT_DIM + j];
        out[g * OUT_DIM + j] = acc;
    }
}

extern "C" void kernel_launch(void* const* d_in, const int* in_sizes, int n_in,
                              void* d_out, int out_size, void* d_ws, size_t ws_size,
                              hipStream_t stream){
    const float* x    = (const float*)d_in[0];
    const int*   ei   = (const int*)  d_in[1];
    const int*   batch= (const int*)  d_in[2];
    const int*   ntime= (const int*)  d_in[3];
    const float* W1   = (const float*)d_in[4];
    const float* as1w = (const float*)d_in[5];
    const float* ad1w = (const float*)d_in[6];
    const float* b1   = (const float*)d_in[7];
    const float* g1   = (const float*)d_in[8];
    const float* be1  = (const float*)d_in[9];
    const float* W2   = (const float*)d_in[10];
    const float* as2w = (const float*)d_in[11];
    const float* ad2w = (const float*)d_in[12];
    const float* b2   = (const float*)d_in[13];
    const float* g2   = (const float*)d_in[14];
    const float* be2  = (const float*)d_in[15];
    const float* Wih  = (const float*)d_in[16];
    const float* Whh  = (const float*)d_in[17];
    const float* bih  = (const float*)d_in[18];
    const float* bhh  = (const float*)d_in[19];
    const float* Wfc  = (const float*)d_in[20];
    const float* bfc  = (const float*)d_in[21];
    float* out = (float*)d_out;

    char* w = (char*)d_ws;
    auto alloc = [&](size_t bytes)->char*{
        char* p = w;
        w += (bytes + 255) & ~size_t(255);
        return p;
    };
    float* h1_act = (float*)alloc((size_t)N_NODES * 256 * 4);
    float* gx     = (float*)alloc((size_t)N_NODES * 256 * 4);
    float* h2_pre = (float*)alloc((size_t)N_NODES * 64 * 4);
    float* xseq   = (float*)alloc((size_t)G_GRAPHS * T_STEPS * 64 * 4);
    float* as1    = (float*)alloc((size_t)N_NODES * 4 * 4);
    float* ad1    = (float*)alloc((size_t)N_NODES * 4 * 4);
    float* as2    = (float*)alloc((size_t)N_NODES * 4);
    float* ad2    = (float*)alloc((size_t)N_NODES * 4);
    float* waS    = (float*)alloc(IN_CH * 4 * 4);
    float* waD    = (float*)alloc(IN_CH * 4 * 4);
    int* counts   = (int*)alloc((size_t)N_NODES * 4);
    int* row_ptr  = (int*)alloc((size_t)(N_NODES + 1) * 4);
    int* cursor   = (int*)alloc((size_t)N_NODES * 4);
    int* ssrc     = (int*)alloc((size_t)EE * 4);

    hipMemsetAsync(counts, 0, (size_t)N_NODES * 4, stream);
    count_k  <<<(EE + 255) / 256, 256, 0, stream>>>(ei, counts);
    scan_k   <<<1, 1024, 0, stream>>>(counts, row_ptr, cursor);
    scatter_k<<<(EE + 255) / 256, 256, 0, stream>>>(ei, cursor, ssrc);
    wa_k     <<<1, 64, 0, stream>>>(W1, as1w, ad1w, waS, waD);
    ns_k     <<<N_NODES / 256, 256, 0, stream>>>(x, waS, waD, as1, ad1);
    gat1_aggx<<<N_NODES / 4, 256, 0, stream>>>(x, as1, ad1, row_ptr, ssrc, W1, b1, g1, be1, h1_act);
    gat2_tr  <<<N_NODES / TM, 256, 0, stream>>>(h1_act, W2, as2w, ad2w, h2_pre, as2, ad2);
    gat2_agg <<<N_NODES / 4, 256, 0, stream>>>(h2_pre, as2, ad2, row_ptr, ssrc, b2, g2, be2, batch, ntime, xseq);
    gx_k     <<<dim3(N_NODES / 64, 2), 256, 0, stream>>>(xseq, Wih, bih, bhh, gx);
    lstm_k   <<<G_GRAPHS, 256, 0, stream>>>(gx, Whh, Wfc, bfc, out);
}

// Round 5
// 291.411 us; speedup vs baseline: 1.2088x; 1.2088x over previous
//
#include <hip/hip_runtime.h>

#define N_NODES 25600
#define N_EDGES 204800
#define EE (N_EDGES + N_NODES)   // 230400 edges incl. self loops
#define IN_CH 6
#define HID 64
#define HEADS 4
#define G_GRAPHS 512
#define T_STEPS 50
#define OUT_DIM 30
#define NEG_SLOPE 0.2f
#define BN_INV 0.9999950000374997f   // 1/sqrt(1+1e-5)

__device__ __forceinline__ float lrelu_(float x){ return x > 0.f ? x : NEG_SLOPE * x; }
__device__ __forceinline__ float elu_(float x){ return x > 0.f ? x : __expf(x) - 1.f; }
__device__ __forceinline__ float sigmoid_(float x){
    return __builtin_amdgcn_rcpf(1.f + __expf(-x));
}
// stable fast tanh: 1 - 2/(1+e^{2x})
__device__ __forceinline__ float tanh_(float x){
    return 1.f - 2.f * __builtin_amdgcn_rcpf(1.f + __expf(2.f * x));
}

// ---------------- CSR build (sort edges by dst) ----------------
__global__ void count_k(const int* __restrict__ ei, int* __restrict__ counts){
    int e = blockIdx.x * 256 + threadIdx.x;
    if (e >= EE) return;
    int dst = (e < N_EDGES) ? ei[N_EDGES + e] : (e - N_EDGES);
    atomicAdd(&counts[dst], 1);
}

__global__ void scan_k(const int* __restrict__ counts, int* __restrict__ row_ptr,
                       int* __restrict__ cursor){
    __shared__ int part[1024];
    int t = threadIdx.x;
    const int CH = N_NODES / 1024;           // 25
    int base = t * CH;
    int s = 0;
    for (int i = 0; i < CH; i++) s += counts[base + i];
    part[t] = s;
    __syncthreads();
    for (int off = 1; off < 1024; off <<= 1){
        int v = (t >= off) ? part[t - off] : 0;
        __syncthreads();
        part[t] += v;
        __syncthreads();
    }
    int run = (t > 0) ? part[t - 1] : 0;
    for (int i = 0; i < CH; i++){
        int cv = counts[base + i];
        row_ptr[base + i] = run;
        cursor[base + i]  = run;
        run += cv;
    }
    if (t == 1023) row_ptr[N_NODES] = run;
}

__global__ void scatter_k(const int* __restrict__ ei, int* __restrict__ cursor,
                          int* __restrict__ ssrc){
    int e = blockIdx.x * 256 + threadIdx.x;
    if (e >= EE) return;
    int src, dst;
    if (e < N_EDGES){ src = ei[e]; dst = ei[N_EDGES + e]; }
    else            { src = dst = e - N_EDGES; }
    int pos = atomicAdd(&cursor[dst], 1);
    ssrc[pos] = src;
}

// ---------------- layer-1 per-node scores (wa fused in: tiny redundant per-block) ----------
// waS[k][h] = sum_c W1[k][h*64+c]*a_src[h][c]; as1[n][h] = x[n].waS[:,h]  (ad likewise)
__global__ void ns_k(const float* __restrict__ x, const float* __restrict__ W1,
                     const float* __restrict__ asw, const float* __restrict__ adw,
                     float* __restrict__ as1, float* __restrict__ ad1){
    __shared__ float waS[IN_CH * 4], waD[IN_CH * 4];
    int t = threadIdx.x;
    if (t < 48){
        int k = t >> 3, h = (t >> 1) & 3, which = t & 1;
        const float* a = which ? adw : asw;
        float s = 0.f;
        #pragma unroll
        for (int c = 0; c < 64; c++) s += W1[k * 256 + h * 64 + c] * a[h * 64 + c];
        (which ? waD : waS)[k * 4 + h] = s;
    }
    __syncthreads();
    int n = blockIdx.x * 256 + t;
    float xv[IN_CH];
    #pragma unroll
    for (int k = 0; k < IN_CH; k++) xv[k] = x[n * IN_CH + k];
    float sv[4] = {0.f, 0.f, 0.f, 0.f}, dv[4] = {0.f, 0.f, 0.f, 0.f};
    #pragma unroll
    for (int k = 0; k < IN_CH; k++){
        #pragma unroll
        for (int h = 0; h < 4; h++){
            sv[h] += xv[k] * waS[k * 4 + h];
            dv[h] += xv[k] * waD[k * 4 + h];
        }
    }
    *(float4*)&as1[n * 4] = make_float4(sv[0], sv[1], sv[2], sv[3]);
    *(float4*)&ad1[n * 4] = make_float4(dv[0], dv[1], dv[2], dv[3]);
}

// ---------------- GAT layer 1: aggregate in x-space, then transform (linearity) ----------
__global__ void gat1_aggx(const float* __restrict__ x, const float* __restrict__ as1,
                          const float* __restrict__ ad1, const int* __restrict__ row_ptr,
                          const int* __restrict__ ssrc, const float* __restrict__ W1,
                          const float* __restrict__ b1, const float* __restrict__ g1,
                          const float* __restrict__ be1, float* __restrict__ h1_act){
    __shared__ float w1s[IN_CH * 256];   // 6 KB
    int tid = threadIdx.x;
    for (int i = tid; i < IN_CH * 256; i += 256) w1s[i] = W1[i];
    __syncthreads();
    int wv = tid >> 6, lane = tid & 63;
    int n = blockIdx.x * 4 + wv;
    int s0 = row_ptr[n], s1 = row_ptr[n + 1];
    float4 adn = *(const float4*)&ad1[n * 4];
    float xs0[IN_CH] = {}, xs1[IN_CH] = {}, xs2[IN_CH] = {}, xs3[IN_CH] = {};
    float d0 = 0.f, d1 = 0.f, d2 = 0.f, d3 = 0.f;
    for (int j = s0; j < s1; j++){
        int s = ssrc[j];
        float4 as = *(const float4*)&as1[s * 4];
        float e0 = __expf(lrelu_(as.x + adn.x));
        float e1 = __expf(lrelu_(as.y + adn.y));
        float e2 = __expf(lrelu_(as.z + adn.z));
        float e3 = __expf(lrelu_(as.w + adn.w));
        d0 += e0; d1 += e1; d2 += e2; d3 += e3;
        const float2* xp = (const float2*)(x + (size_t)s * IN_CH);  // s*6 even -> 8B aligned
        float2 xa = xp[0], xb = xp[1], xc = xp[2];
        float xv[IN_CH] = {xa.x, xa.y, xb.x, xb.y, xc.x, xc.y};
        #pragma unroll
        for (int k = 0; k < IN_CH; k++){
            xs0[k] += e0 * xv[k];
            xs1[k] += e1 * xv[k];
            xs2[k] += e2 * xv[k];
            xs3[k] += e3 * xv[k];
        }
    }
    float r0 = 1.f / d0, r1 = 1.f / d1, r2 = 1.f / d2, r3 = 1.f / d3;
    #pragma unroll
    for (int h = 0; h < 4; h++){
        const float* xsh = (h == 0) ? xs0 : (h == 1) ? xs1 : (h == 2) ? xs2 : xs3;
        float rh = (h == 0) ? r0 : (h == 1) ? r1 : (h == 2) ? r2 : r3;
        int col = h * 64 + lane;
        float acc = 0.f;
        #pragma unroll
        for (int k = 0; k < IN_CH; k++) acc += xsh[k] * w1s[k * 256 + col];
        float v = acc * rh + b1[col];
        v = g1[col] * (v * BN_INV) + be1[col];
        h1_act[(size_t)n * 256 + col] = elu_(v);
    }
}

// ---------------- GAT layer 2 transform: tiled SGEMM h2_pre = h1_act @ W2 + fused scores ----
#define TM 64
#define KT 32
#define APAD 4
__global__ __launch_bounds__(256) void gat2_tr(const float* __restrict__ h1_act,
                        const float* __restrict__ W2,
                        const float* __restrict__ asw, const float* __restrict__ adw,
                        float* __restrict__ h2_pre, float* __restrict__ as2,
                        float* __restrict__ ad2){
    __shared__ float As[TM][KT + APAD];
    __shared__ float Bs[KT][64];
    int tx = threadIdx.x;
    int rg = tx >> 4;
    int cg = tx & 15;
    int r0 = rg * 4, c0 = cg * 4;
    int rowBase = blockIdx.x * TM;
    float acc[4][4] = {};
    for (int k0 = 0; k0 < 256; k0 += KT){
        #pragma unroll
        for (int it = 0; it < 2; it++){
            int i = tx + it * 256;
            int row = i >> 3;
            int c4  = (i & 7) * 4;
            *(float4*)&As[row][c4] =
                *(const float4*)(h1_act + (size_t)(rowBase + row) * 256 + k0 + c4);
        }
        #pragma unroll
        for (int it = 0; it < 2; it++){
            int i = tx + it * 256;
            int row = i >> 4;
            int c4  = (i & 15) * 4;
            *(float4*)&Bs[row][c4] = *(const float4*)(W2 + (size_t)(k0 + row) * 64 + c4);
        }
        __syncthreads();
        #pragma unroll
        for (int kq = 0; kq < KT; kq += 4){
            float4 b0 = *(float4*)&Bs[kq + 0][c0];
            float4 b1v = *(float4*)&Bs[kq + 1][c0];
            float4 b2v = *(float4*)&Bs[kq + 2][c0];
            float4 b3 = *(float4*)&Bs[kq + 3][c0];
            #pragma unroll
            for (int i = 0; i < 4; i++){
                float4 a = *(float4*)&As[r0 + i][kq];
                acc[i][0] += a.x * b0.x + a.y * b1v.x + a.z * b2v.x + a.w * b3.x;
                acc[i][1] += a.x * b0.y + a.y * b1v.y + a.z * b2v.y + a.w * b3.y;
                acc[i][2] += a.x * b0.z + a.y * b1v.z + a.z * b2v.z + a.w * b3.z;
                acc[i][3] += a.x * b0.w + a.y * b1v.w + a.z * b2v.w + a.w * b3.w;
            }
        }
        __syncthreads();
    }
    float aw0 = asw[c0], aw1 = asw[c0+1], aw2 = asw[c0+2], aw3 = asw[c0+3];
    float dw0 = adw[c0], dw1 = adw[c0+1], dw2 = adw[c0+2], dw3 = adw[c0+3];
    #pragma unroll
    for (int i = 0; i < 4; i++){
        int row = rowBase + r0 + i;
        *(float4*)(h2_pre + (size_t)row * 64 + c0) =
            make_float4(acc[i][0], acc[i][1], acc[i][2], acc[i][3]);
        float sA = acc[i][0]*aw0 + acc[i][1]*aw1 + acc[i][2]*aw2 + acc[i][3]*aw3;
        float sD = acc[i][0]*dw0 + acc[i][1]*dw1 + acc[i][2]*dw2 + acc[i][3]*dw3;
        #pragma unroll
        for (int off = 8; off; off >>= 1){
            sA += __shfl_xor(sA, off);
            sD += __shfl_xor(sD, off);
        }
        if (cg == 0){ as2[row] = sA; ad2[row] = sD; }
    }
}

// ---------------- GAT layer 2 aggregate + bias + BN + ELU + FUSED Wih projection ----------
// Block = 16 nodes. Wave wv aggregates nodes nbase+4wv..+3 (4x unrolled prefetched edge
// loop), writes activated v to LDS; one barrier; then all 256 threads project:
// gx[pos*256+tx] = Wih[tx].v + (bih+bhh)[tx].  Wih row register-resident (64 VGPR).
// Eliminates the xseq intermediate and the gx_k GEMM entirely.
__global__ __launch_bounds__(256, 2) void gat2_aggp(const float* __restrict__ h2_pre,
        const float* __restrict__ as2, const float* __restrict__ ad2,
        const int* __restrict__ row_ptr, const int* __restrict__ ssrc,
        const float* __restrict__ b2, const float* __restrict__ g2,
        const float* __restrict__ be2,
        const int* __restrict__ batch, const int* __restrict__ ntime,
        const float* __restrict__ Wih, const float* __restrict__ bih,
        const float* __restrict__ bhh, float* __restrict__ gx){
    __shared__ float vsh[16][64];
    __shared__ int posb[16];
    int tx = threadIdx.x, wv = tx >> 6, lane = tx & 63;
    float4 wih[16];
    const float4* Wr = (const float4*)(Wih + tx * 64);
    #pragma unroll
    for (int k = 0; k < 16; k++) wih[k] = Wr[k];
    float bsum = bih[tx] + bhh[tx];
    int nbase = blockIdx.x * 16;
    for (int q = 0; q < 4; q++){
        int n = nbase + wv * 4 + q;
        int s0 = row_ptr[n], s1 = row_ptr[n + 1];
        float adn = ad2[n];
        float denom = 0.f, acc = 0.f;
        int j = s0;
        for (; j + 4 <= s1; j += 4){
            int sa = ssrc[j], sb = ssrc[j + 1], sc = ssrc[j + 2], sd = ssrc[j + 3];
            float ea = __expf(lrelu_(as2[sa] + adn));
            float eb = __expf(lrelu_(as2[sb] + adn));
            float ec = __expf(lrelu_(as2[sc] + adn));
            float ed = __expf(lrelu_(as2[sd] + adn));
            float ha = h2_pre[(size_t)sa * 64 + lane];
            float hb = h2_pre[(size_t)sb * 64 + lane];
            float hc = h2_pre[(size_t)sc * 64 + lane];
            float hd = h2_pre[(size_t)sd * 64 + lane];
            denom += (ea + eb) + (ec + ed);
            acc += ea * ha + eb * hb + ec * hc + ed * hd;
        }
        for (; j < s1; j++){
            int s = ssrc[j];
            float e = __expf(lrelu_(as2[s] + adn));
            denom += e;
            acc += e * h2_pre[(size_t)s * 64 + lane];
        }
        float v = acc / denom + b2[lane];
        v = g2[lane] * (v * BN_INV) + be2[lane];
        vsh[wv * 4 + q][lane] = elu_(v);
        if (lane == 0) posb[wv * 4 + q] = batch[n] * T_STEPS + ntime[n];
    }
    __syncthreads();
    #pragma unroll
    for (int q = 0; q < 16; q++){
        const float4* vp = (const float4*)vsh[q];
        float a0 = 0.f, a1 = 0.f, a2 = 0.f, a3 = 0.f;
        #pragma unroll
        for (int k = 0; k < 16; k++){
            float4 vv = vp[k];
            float4 ww = wih[k];
            a0 += ww.x * vv.x;
            a1 += ww.y * vv.y;
            a2 += ww.z * vv.z;
            a3 += ww.w * vv.w;
        }
        gx[(size_t)posb[q] * 256 + tx] = bsum + (a0 + a1) + (a2 + a3);
    }
}

// ---------------- LSTM over T=50 steps + final FC, one block per graph ----------------
// Round-2 structure (measured 46.4 us, VGPR 48, no spill): h in per-wave LDS copy
// (double-buffered, 16 same-address b128 broadcasts), gates double-buffered -> one
// barrier per step; gx loaded in-loop (1 coalesced dword per thread per step).
__global__ __launch_bounds__(256, 2) void lstm_k(const float* __restrict__ gx,
        const float* __restrict__ Whh,
        const float* __restrict__ Wfc, const float* __restrict__ bfc,
        float* __restrict__ out){
    int g = blockIdx.x;
    int j = threadIdx.x;
    int wv = j >> 6, lane = j & 63;
    __shared__ float gates[2][256];
    __shared__ float hb[4][2][64];     // per-wave h copy, double-buffered
    float4 whh[16];
    const float4* Hr = (const float4*)(Whh + j * 64);
    #pragma unroll
    for (int k = 0; k < 16; k++) whh[k] = Hr[k];
    float c = 0.f;
    hb[wv][0][lane] = 0.f;             // own-wave init; within-wave ordering via lgkmcnt
    const float* gxg = gx + (size_t)g * T_STEPS * 256;
    float gxv = gxg[j];
    float hn = 0.f;
    for (int t = 0; t < T_STEPS; t++){
        float gx_next = (t + 1 < T_STEPS) ? gxg[(t + 1) * 256 + j] : 0.f;
        int buf = t & 1;
        const float4* hp = (const float4*)hb[wv][buf];
        float a0 = gxv, a1 = 0.f, a2 = 0.f, a3 = 0.f;
        #pragma unroll
        for (int k = 0; k < 16; k++){
            float4 hv = hp[k];
            float4 wvv = whh[k];
            a0 += wvv.x * hv.x;
            a1 += wvv.y * hv.y;
            a2 += wvv.z * hv.z;
            a3 += wvv.w * hv.w;
        }
        gates[buf][j] = (a0 + a1) + (a2 + a3);
        __syncthreads();
        float iv = gates[buf][lane];
        float fv = gates[buf][64 + lane];
        float gv = gates[buf][128 + lane];
        float ov = gates[buf][192 + lane];
        c = sigmoid_(fv) * c + sigmoid_(iv) * tanh_(gv);
        hn = sigmoid_(ov) * tanh_(c);
        hb[wv][buf ^ 1][lane] = hn;    // own-wave copy for next step, no barrier needed
        gxv = gx_next;
    }
    // final FC
    if (wv == 0) gates[0][lane] = hn;
    __syncthreads();
    if (j < OUT_DIM){
        float acc = bfc[j];
        #pragma unroll
        for (int k = 0; k < 64; k++) acc += gates[0][k] * Wfc[k * OUT_DIM + j];
        out[g * OUT_DIM + j] = acc;
    }
}

extern "C" void kernel_launch(void* const* d_in, const int* in_sizes, int n_in,
                              void* d_out, int out_size, void* d_ws, size_t ws_size,
                              hipStream_t stream){
    const float* x    = (const float*)d_in[0];
    const int*   ei   = (const int*)  d_in[1];
    const int*   batch= (const int*)  d_in[2];
    const int*   ntime= (const int*)  d_in[3];
    const float* W1   = (const float*)d_in[4];
    const float* as1w = (const float*)d_in[5];
    const float* ad1w = (const float*)d_in[6];
    const float* b1   = (const float*)d_in[7];
    const float* g1   = (const float*)d_in[8];
    const float* be1  = (const float*)d_in[9];
    const float* W2   = (const float*)d_in[10];
    const float* as2w = (const float*)d_in[11];
    const float* ad2w = (const float*)d_in[12];
    const float* b2   = (const float*)d_in[13];
    const float* g2   = (const float*)d_in[14];
    const float* be2  = (const float*)d_in[15];
    const float* Wih  = (const float*)d_in[16];
    const float* Whh  = (const float*)d_in[17];
    const float* bih  = (const float*)d_in[18];
    const float* bhh  = (const float*)d_in[19];
    const float* Wfc  = (const float*)d_in[20];
    const float* bfc  = (const float*)d_in[21];
    float* out = (float*)d_out;

    char* w = (char*)d_ws;
    auto alloc = [&](size_t bytes)->char*{
        char* p = w;
        w += (bytes + 255) & ~size_t(255);
        return p;
    };
    float* h1_act = (float*)alloc((size_t)N_NODES * 256 * 4);
    float* gx     = (float*)alloc((size_t)N_NODES * 256 * 4);
    float* h2_pre = (float*)alloc((size_t)N_NODES * 64 * 4);
    float* as1    = (float*)alloc((size_t)N_NODES * 4 * 4);
    float* ad1    = (float*)alloc((size_t)N_NODES * 4 * 4);
    float* as2    = (float*)alloc((size_t)N_NODES * 4);
    float* ad2    = (float*)alloc((size_t)N_NODES * 4);
    int* counts   = (int*)alloc((size_t)N_NODES * 4);
    int* row_ptr  = (int*)alloc((size_t)(N_NODES + 1) * 4);
    int* cursor   = (int*)alloc((size_t)N_NODES * 4);
    int* ssrc     = (int*)alloc((size_t)EE * 4);

    hipMemsetAsync(counts, 0, (size_t)N_NODES * 4, stream);
    count_k  <<<(EE + 255) / 256, 256, 0, stream>>>(ei, counts);
    scan_k   <<<1, 1024, 0, stream>>>(counts, row_ptr, cursor);
    scatter_k<<<(EE + 255) / 256, 256, 0, stream>>>(ei, cursor, ssrc);
    ns_k     <<<N_NODES / 256, 256, 0, stream>>>(x, W1, as1w, ad1w, as1, ad1);
    gat1_aggx<<<N_NODES / 4, 256, 0, stream>>>(x, as1, ad1, row_ptr, ssrc, W1, b1, g1, be1, h1_act);
    gat2_tr  <<<N_NODES / TM, 256, 0, stream>>>(h1_act, W2, as2w, ad2w, h2_pre, as2, ad2);
    gat2_aggp<<<N_NODES / 16, 256, 0, stream>>>(h2_pre, as2, ad2, row_ptr, ssrc, b2, g2, be2,
                                                batch, ntime, Wih, bih, bhh, gx);
    lstm_k   <<<G_GRAPHS, 256, 0, stream>>>(gx, Whh, Wfc, bfc, out);
}